// Round 4
// baseline (56.273 us; speedup 1.0000x reference)
//
#include <hip/hip_runtime.h>

// out[t*768 + e] = weight[e*VOCAB + x[t]]
// Counting-sort tokens into 32-col windows; per (window,row-group) block:
// stage 128x32 f32 slab into LDS via global_load_lds dwordx4 (1 inst/granule,
// XOR-swizzled source so serve reads don't hit a single bank), serve bucket
// tokens from LDS with coalesced 256B output stores.

#define VOCAB 50257
#define EMBED 768
#define WINB 32
#define NWIN 1571          // ceil(VOCAB/32)
#define NWIN_P 2048
#define RG 6               // row groups
#define ROWS 128           // EMBED / RG
#define CHUNK 256

__global__ __launch_bounds__(256) void hist_kernel(const int* __restrict__ x,
                                                   int* __restrict__ cnt, int n) {
  int i = blockIdx.x * blockDim.x + threadIdx.x;
  if (i < n) atomicAdd(&cnt[x[i] >> 5], 1);
}

__global__ __launch_bounds__(1024) void scan_kernel(const int* __restrict__ cnt,
                                                    int* __restrict__ off,
                                                    int* __restrict__ cur) {
  __shared__ int a[NWIN_P], b[NWIN_P];
  int t = threadIdx.x;
  a[t] = cnt[t];
  a[t + 1024] = cnt[t + 1024];
  __syncthreads();
  int* src = a; int* dst = b;
  for (int d = 1; d < NWIN_P; d <<= 1) {
    for (int i = t; i < NWIN_P; i += 1024)
      dst[i] = (i >= d) ? src[i] + src[i - d] : src[i];
    __syncthreads();
    int* tmp = src; src = dst; dst = tmp;
  }
  for (int i = t; i < NWIN_P; i += 1024) {
    int e = (i > 0) ? src[i - 1] : 0;
    off[i] = e;
    cur[i] = e;
  }
}

__global__ __launch_bounds__(256) void scatter_kernel(const int* __restrict__ x,
                                                      int* __restrict__ cur,
                                                      int* __restrict__ sorted,
                                                      int n) {
  int i = blockIdx.x * blockDim.x + threadIdx.x;
  if (i < n) {
    int v = x[i];
    int p = atomicAdd(&cur[v >> 5], 1);
    sorted[p] = (i << 5) | (v & 31);
  }
}

__device__ __forceinline__ int xcd_swizzle(int bid, int nwg) {
  const int NX = 8;
  int q = nwg / NX, r = nwg % NX;
  int xcd = bid % NX, idx = bid / NX;
  int base = (xcd < r) ? xcd * (q + 1) : r * (q + 1) + (xcd - r) * q;
  return base + idx;
}

__global__ __launch_bounds__(256) void gather_kernel(const float* __restrict__ w,
                                                     const int* __restrict__ off,
                                                     const int* __restrict__ sorted,
                                                     float* __restrict__ out) {
  __shared__ float lds[ROWS * WINB];   // 16 KB, granule-swizzled image
  __shared__ int toks[CHUNK];
  const int logical = xcd_swizzle(blockIdx.x, NWIN * RG);
  const int wid = logical % NWIN;
  const int rg  = logical / NWIN;
  const int row0 = rg * ROWS;
  const int col0 = wid * WINB;
  const int tid = threadIdx.x;
  const int wave = tid >> 6, lane = tid & 63;

  int beg = off[wid], end = off[wid + 1];

  if (wid != NWIN - 1) {
    // granule p = k*256 + tid; row r = p>>3, swizzled slot c4s = p&7.
    // Source granule c4 = c4s ^ ((r>>2)&7) -> serve reads spread over 8 banks.
    #pragma unroll
    for (int k = 0; k < ROWS * 8 / 256; ++k) {
      int p = k * 256 + tid;
      int r = p >> 3;
      int c4 = (p & 7) ^ ((r >> 2) & 7);
      const float* src = &w[(size_t)(row0 + r) * VOCAB + col0 + (c4 << 2)];
      float* dst = &lds[(k * 1024 + wave * 256)];   // wave-uniform; lane adds *16B
      __builtin_amdgcn_global_load_lds(
          (const __attribute__((address_space(1))) void*)src,
          (__attribute__((address_space(3))) void*)dst, 16, 0, 0);
    }
  } else {
    // last window: 17 valid cols, guarded scalar staging into swizzled layout
    for (int j = tid; j < ROWS * WINB; j += 256) {
      int r = j >> 5, cc = j & 31;
      int c = col0 + cc;
      float v = (c < VOCAB) ? w[(size_t)(row0 + r) * VOCAB + c] : 0.f;
      lds[r * WINB + ((((cc >> 2) ^ ((r >> 2) & 7)) << 2) | (cc & 3))] = v;
    }
  }

  int m = end - beg; if (m > CHUNK) m = CHUNK;
  if (tid < m) toks[tid] = sorted[beg + tid];
  __syncthreads();   // drains vmcnt for global_load_lds

  const int xorv = (lane >> 2) & 7;   // == ((k*64+lane)>>2)&7 for all k
  while (true) {
    for (int i = wave; i < m; i += 4) {
      int pk = toks[i];               // LDS broadcast
      int t = pk >> 5, cc = pk & 31;
      int slot = (((cc >> 2) ^ xorv) << 2) | (cc & 3);
      float* o = &out[(size_t)t * EMBED + row0];
      #pragma unroll
      for (int k = 0; k < ROWS / 64; ++k)
        o[k * 64 + lane] = lds[(k * 64 + lane) * WINB + slot];
    }
    beg += m;
    if (beg >= end) break;
    __syncthreads();
    m = end - beg; if (m > CHUNK) m = CHUNK;
    if (tid < m) toks[tid] = sorted[beg + tid];
    __syncthreads();
  }
}

extern "C" void kernel_launch(void* const* d_in, const int* in_sizes, int n_in,
                              void* d_out, int out_size, void* d_ws, size_t ws_size,
                              hipStream_t stream) {
  const int*   x = (const int*)d_in[0];
  const float* w = (const float*)d_in[1];
  float* out = (float*)d_out;
  const int n = in_sizes[0];          // 16384 tokens

  int* cnt    = (int*)d_ws;           // [2048]
  int* off    = cnt + NWIN_P;         // [2048]
  int* cur    = off + NWIN_P;         // [2048]
  int* sorted = cur + NWIN_P;         // [n]

  hipMemsetAsync(cnt, 0, NWIN_P * sizeof(int), stream);
  hist_kernel<<<(n + 255) / 256, 256, 0, stream>>>(x, cnt, n);
  scan_kernel<<<1, 1024, 0, stream>>>(cnt, off, cur);
  scatter_kernel<<<(n + 255) / 256, 256, 0, stream>>>(x, cur, sorted, n);
  gather_kernel<<<NWIN * RG, 256, 0, stream>>>(w, off, sorted, out);
}